// Round 1
// baseline (1909.438 us; speedup 1.0000x reference)
//
#include <hip/hip_runtime.h>

typedef float f4 __attribute__((ext_vector_type(4)));
typedef float f2 __attribute__((ext_vector_type(2)));

#define N_NODES 100000

// ---------------- CSR build ----------------

__global__ void k_count(const int* __restrict__ dst, int* __restrict__ deg, int E) {
    int e = blockIdx.x * 256 + threadIdx.x;
    if (e < E) atomicAdd(&deg[dst[e]], 1);
}

__global__ void k_scan1(const int* __restrict__ deg, int* __restrict__ rp,
                        int* __restrict__ bsum, int n) {
    __shared__ int s[256];
    int tid = threadIdx.x, gid = blockIdx.x * 256 + tid;
    int v = gid < n ? deg[gid] : 0;
    s[tid] = v;
    __syncthreads();
    for (int off = 1; off < 256; off <<= 1) {
        int t = (tid >= off) ? s[tid - off] : 0;
        __syncthreads();
        s[tid] += t;
        __syncthreads();
    }
    if (gid < n) rp[gid] = s[tid] - v;   // in-block exclusive
    if (tid == 255) bsum[blockIdx.x] = s[255];
}

__global__ void k_scan2(int* bsum, int nb) {
    __shared__ int s[512];
    int tid = threadIdx.x;
    int v = (tid < nb) ? bsum[tid] : 0;
    s[tid] = v;
    __syncthreads();
    for (int off = 1; off < 512; off <<= 1) {
        int t = (tid >= off) ? s[tid - off] : 0;
        __syncthreads();
        s[tid] += t;
        __syncthreads();
    }
    if (tid < nb) bsum[tid] = s[tid] - v;  // exclusive scan of block sums
}

__global__ void k_fin(const int* __restrict__ deg, int* __restrict__ rp,
                      const int* __restrict__ bsum, float* __restrict__ invd,
                      int n, int E) {
    int gid = blockIdx.x * 256 + threadIdx.x;
    if (gid < n) {
        rp[gid] += bsum[gid >> 8];
        invd[gid] = 1.0f / fmaxf((float)deg[gid], 1.0f);
    }
    if (gid == 0) rp[n] = E;
}

__global__ void k_scatter(const int* __restrict__ src, const int* __restrict__ dst,
                          const int* __restrict__ rp, int* __restrict__ cnt,
                          int* __restrict__ col, int E) {
    int e = blockIdx.x * 256 + threadIdx.x;
    if (e >= E) return;
    int d = dst[e];
    int pos = rp[d] + atomicAdd(&cnt[d], 1);
    col[pos] = src[e];
}

// ---------------- mean aggregation (CSR gather, 1 wave per node) ----------------

__global__ __launch_bounds__(256) void k_agg(const float* __restrict__ h,
                                             const int* __restrict__ rp,
                                             const int* __restrict__ col,
                                             const float* __restrict__ invd,
                                             float* __restrict__ out, int n) {
    int gw = (blockIdx.x * 256 + threadIdx.x) >> 6;  // one wave per node
    int lane = threadIdx.x & 63;
    if (gw >= n) return;
    int beg = rp[gw], end = rp[gw + 1];
    float ax = 0.f, ay = 0.f;
    for (int e = beg; e < end; ++e) {
        int s = col[e];
        f2 v = *(const f2*)&h[s * 128 + lane * 2];
        ax += v[0];
        ay += v[1];
    }
    float iv = invd[gw];
    f2 r;
    r[0] = ax * iv;
    r[1] = ay * iv;
    *(f2*)&out[gw * 128 + lane * 2] = r;
}

// ---------------- fused dual GEMM: out = h@Ws + nb@Wn + b (optional relu) -------
// 64-row tile in LDS, 256 threads, each thread computes 4 rows x 8 cols.

__global__ __launch_bounds__(256) void gemm128(const float* __restrict__ h,
                                               const float* __restrict__ nb,
                                               const float* __restrict__ ws,
                                               const float* __restrict__ wn,
                                               const float* __restrict__ bias,
                                               float* __restrict__ out,
                                               int M, int relu) {
    __shared__ float sh[64][128];
    __shared__ float sn[64][128];
    const int tid = threadIdx.x;
    const int r0 = blockIdx.x * 64;

#pragma unroll
    for (int i = 0; i < 8; ++i) {
        int idx = tid + i * 256;        // float4 index in [0,2048)
        int row = idx >> 5;
        int kq = (idx & 31) << 2;
        int gr = r0 + row;
        if (gr > M - 1) gr = M - 1;
        *(f4*)&sh[row][kq] = *(const f4*)&h[(size_t)gr * 128 + kq];
        *(f4*)&sn[row][kq] = *(const f4*)&nb[(size_t)gr * 128 + kq];
    }
    __syncthreads();

    const int tc = (tid & 15) * 8;   // col base (0..120)
    const int tr = (tid >> 4) * 4;   // row base (0..60)

    float acc[4][8];
#pragma unroll
    for (int i = 0; i < 4; ++i)
#pragma unroll
        for (int j = 0; j < 8; ++j) acc[i][j] = 0.f;

    for (int kb = 0; kb < 128; kb += 4) {
        f4 as[4], an[4];
#pragma unroll
        for (int i = 0; i < 4; ++i) {
            as[i] = *(const f4*)&sh[tr + i][kb];
            an[i] = *(const f4*)&sn[tr + i][kb];
        }
#pragma unroll
        for (int kk = 0; kk < 4; ++kk) {
            const int k = kb + kk;
            f4 s0 = *(const f4*)&ws[k * 128 + tc];
            f4 s1 = *(const f4*)&ws[k * 128 + tc + 4];
            f4 n0 = *(const f4*)&wn[k * 128 + tc];
            f4 n1 = *(const f4*)&wn[k * 128 + tc + 4];
#pragma unroll
            for (int i = 0; i < 4; ++i) {
                float a = as[i][kk];
                float bb = an[i][kk];
#pragma unroll
                for (int j = 0; j < 4; ++j) {
                    acc[i][j] += a * s0[j] + bb * n0[j];
                    acc[i][4 + j] += a * s1[j] + bb * n1[j];
                }
            }
        }
    }

#pragma unroll
    for (int i = 0; i < 4; ++i) {
        int gr = r0 + tr + i;
        if (gr < M) {
            f4 o0, o1;
#pragma unroll
            for (int j = 0; j < 4; ++j) {
                float v0 = acc[i][j] + bias[tc + j];
                float v1 = acc[i][4 + j] + bias[tc + 4 + j];
                if (relu) {
                    v0 = fmaxf(v0, 0.f);
                    v1 = fmaxf(v1, 0.f);
                }
                o0[j] = v0;
                o1[j] = v1;
            }
            *(f4*)&out[(size_t)gr * 128 + tc] = o0;
            *(f4*)&out[(size_t)gr * 128 + tc + 4] = o1;
        }
    }
}

// ---------------- final GEMM 128 -> 47 ----------------
// Weights in LDS; each wave owns 8 rows held in registers, k broadcast by readlane.

__device__ inline float rdlane(float v, int l) {
    return __builtin_bit_cast(float, __builtin_amdgcn_readlane(__builtin_bit_cast(int, v), l));
}

__global__ __launch_bounds__(256) void gemm_out47(const float* __restrict__ h,
                                                  const float* __restrict__ nb,
                                                  const float* __restrict__ wso,
                                                  const float* __restrict__ wno,
                                                  const float* __restrict__ bo,
                                                  float* __restrict__ out, int M) {
    __shared__ float sws[128 * 48 + 16];
    __shared__ float swn[128 * 48 + 16];
    const int tid = threadIdx.x;
    for (int i = tid; i < 128 * 47; i += 256) {
        int k = i / 47, c = i - k * 47;
        sws[k * 48 + c] = wso[i];
        swn[k * 48 + c] = wno[i];
    }
    __syncthreads();

    const int lane = tid & 63;
    const int wv = tid >> 6;
    const int rbase = blockIdx.x * 32 + wv * 8;

    float hreg[8][2], nreg[8][2];
#pragma unroll
    for (int r = 0; r < 8; ++r) {
        int gr = rbase + r;
        if (gr > M - 1) gr = M - 1;
        hreg[r][0] = h[(size_t)gr * 128 + lane];
        hreg[r][1] = h[(size_t)gr * 128 + 64 + lane];
        nreg[r][0] = nb[(size_t)gr * 128 + lane];
        nreg[r][1] = nb[(size_t)gr * 128 + 64 + lane];
    }

    float acc[8] = {0, 0, 0, 0, 0, 0, 0, 0};
#pragma unroll
    for (int half = 0; half < 2; ++half) {
#pragma unroll 8
        for (int kk = 0; kk < 64; ++kk) {
            int k = (half << 6) + kk;
            float wsv = sws[k * 48 + lane];
            float wnv = swn[k * 48 + lane];
#pragma unroll
            for (int r = 0; r < 8; ++r) {
                acc[r] += rdlane(hreg[r][half], kk) * wsv;
                acc[r] += rdlane(nreg[r][half], kk) * wnv;
            }
        }
    }

    if (lane < 47) {
        float bv = bo[lane];
#pragma unroll
        for (int r = 0; r < 8; ++r) {
            int gr = rbase + r;
            if (gr < M) out[(size_t)gr * 47 + lane] = acc[r] + bv;
        }
    }
}

// ---------------- launch ----------------

extern "C" void kernel_launch(void* const* d_in, const int* in_sizes, int n_in,
                              void* d_out, int out_size, void* d_ws, size_t ws_size,
                              hipStream_t stream) {
    const float* x = (const float*)d_in[0];
    const int* src = (const int*)d_in[1];
    const int* dst = (const int*)d_in[2];
    const float* w_self = (const float*)d_in[3];   // [5][128][128]
    const float* w_neigh = (const float*)d_in[4];  // [5][128][128]
    const float* b = (const float*)d_in[5];        // [5][128]
    const float* wso = (const float*)d_in[6];      // [128][47]
    const float* wno = (const float*)d_in[7];      // [128][47]
    const float* bo = (const float*)d_in[8];       // [47]
    float* out = (float*)d_out;

    const int N = N_NODES;
    const int E = in_sizes[1];

    char* w = (char*)d_ws;
    float* hA = (float*)w;  w += (size_t)N * 128 * 4;
    float* hB = (float*)w;  w += (size_t)N * 128 * 4;
    int* deg = (int*)w;     w += (size_t)N * 4;
    int* rp = (int*)w;      w += (size_t)(N + 4) * 4;
    int* cnt = (int*)w;     w += (size_t)N * 4;
    int* col = (int*)w;     w += (size_t)E * 4;
    int* bsum = (int*)w;    w += 4096;
    float* invd = (float*)w; w += (size_t)N * 4;

    hipMemsetAsync(deg, 0, (size_t)N * 4, stream);
    hipMemsetAsync(cnt, 0, (size_t)N * 4, stream);

    int eb = (E + 255) / 256;
    int nb = (N + 255) / 256;  // 391
    k_count<<<eb, 256, 0, stream>>>(dst, deg, E);
    k_scan1<<<nb, 256, 0, stream>>>(deg, rp, bsum, N);
    k_scan2<<<1, 512, 0, stream>>>(bsum, nb);
    k_fin<<<nb, 256, 0, stream>>>(deg, rp, bsum, invd, N, E);
    k_scatter<<<eb, 256, 0, stream>>>(src, dst, rp, cnt, col, E);

    const int aggBlocks = (N * 64 + 255) / 256;  // 25000
    const int gemmBlocks = (N + 63) / 64;        // 1563

    // layer 0 (no relu): neigh -> hA, gemm writes h1 in-place into hA
    k_agg<<<aggBlocks, 256, 0, stream>>>(x, rp, col, invd, hA, N);
    gemm128<<<gemmBlocks, 256, 0, stream>>>(x, hA, w_self, w_neigh, b, hA, N, 0);

    const float* cur = hA;
    float* nxt = hB;
    for (int l = 1; l < 5; ++l) {
        k_agg<<<aggBlocks, 256, 0, stream>>>(cur, rp, col, invd, nxt, N);
        gemm128<<<gemmBlocks, 256, 0, stream>>>(cur, nxt,
                                                w_self + (size_t)l * 128 * 128,
                                                w_neigh + (size_t)l * 128 * 128,
                                                b + (size_t)l * 128, nxt, N, 1);
        float* t = (float*)cur;
        cur = nxt;
        nxt = t;
    }

    // final layer 128 -> 47
    k_agg<<<aggBlocks, 256, 0, stream>>>(cur, rp, col, invd, nxt, N);
    gemm_out47<<<(N + 31) / 32, 256, 0, stream>>>(cur, nxt, wso, wno, bo, out, N);
}

// Round 2
// 913.956 us; speedup vs baseline: 2.0892x; 2.0892x over previous
//
#include <hip/hip_runtime.h>

typedef float f4 __attribute__((ext_vector_type(4)));
typedef float f32x4 __attribute__((ext_vector_type(4)));
typedef short s16x8 __attribute__((ext_vector_type(8)));

#define N_NODES 100000

__device__ inline unsigned short f2bf(float f) {
    unsigned int u = __builtin_bit_cast(unsigned int, f);
    u += 0x7FFFu + ((u >> 16) & 1u);
    return (unsigned short)(u >> 16);
}
__device__ inline float bflo(unsigned int v) { return __builtin_bit_cast(float, v << 16); }
__device__ inline float bfhi(unsigned int v) { return __builtin_bit_cast(float, v & 0xFFFF0000u); }

// ---------------- CSR build ----------------

__global__ void k_count(const int* __restrict__ dst, int* __restrict__ deg, int E) {
    int e = blockIdx.x * 256 + threadIdx.x;
    if (e < E) atomicAdd(&deg[dst[e]], 1);
}

__global__ void k_scan1(const int* __restrict__ deg, int* __restrict__ rp,
                        int* __restrict__ bsum, int n) {
    __shared__ int s[256];
    int tid = threadIdx.x, gid = blockIdx.x * 256 + tid;
    int v = gid < n ? deg[gid] : 0;
    s[tid] = v;
    __syncthreads();
    for (int off = 1; off < 256; off <<= 1) {
        int t = (tid >= off) ? s[tid - off] : 0;
        __syncthreads();
        s[tid] += t;
        __syncthreads();
    }
    if (gid < n) rp[gid] = s[tid] - v;
    if (tid == 255) bsum[blockIdx.x] = s[255];
}

__global__ void k_scan2(int* bsum, int nb) {
    __shared__ int s[512];
    int tid = threadIdx.x;
    int v = (tid < nb) ? bsum[tid] : 0;
    s[tid] = v;
    __syncthreads();
    for (int off = 1; off < 512; off <<= 1) {
        int t = (tid >= off) ? s[tid - off] : 0;
        __syncthreads();
        s[tid] += t;
        __syncthreads();
    }
    if (tid < nb) bsum[tid] = s[tid] - v;
}

__global__ void k_fin(const int* __restrict__ deg, int* __restrict__ rp,
                      const int* __restrict__ bsum, float* __restrict__ invd,
                      int n, int E) {
    int gid = blockIdx.x * 256 + threadIdx.x;
    if (gid < n) {
        rp[gid] += bsum[gid >> 8];
        invd[gid] = 1.0f / fmaxf((float)deg[gid], 1.0f);
    }
    if (gid == 0) rp[n] = E;
}

__global__ void k_scatter(const int* __restrict__ src, const int* __restrict__ dst,
                          const int* __restrict__ rp, int* __restrict__ cnt,
                          int* __restrict__ col, int E) {
    int e = blockIdx.x * 256 + threadIdx.x;
    if (e >= E) return;
    int d = dst[e];
    int pos = rp[d] + atomicAdd(&cnt[d], 1);
    col[pos] = src[e];
}

// ---------------- prep: f32 -> bf16 conversions / weight packing ----------------

__global__ void k_cvt(const float* __restrict__ x, unsigned short* __restrict__ xb, int n8) {
    int t = blockIdx.x * 256 + threadIdx.x;
    if (t >= n8) return;
    f4 a = *(const f4*)&x[(size_t)t * 8];
    f4 b = *(const f4*)&x[(size_t)t * 8 + 4];
    s16x8 p;
    p[0] = (short)f2bf(a[0]); p[1] = (short)f2bf(a[1]);
    p[2] = (short)f2bf(a[2]); p[3] = (short)f2bf(a[3]);
    p[4] = (short)f2bf(b[0]); p[5] = (short)f2bf(b[1]);
    p[6] = (short)f2bf(b[2]); p[7] = (short)f2bf(b[3]);
    *(s16x8*)&xb[(size_t)t * 8] = p;
}

// pack W^T fragments: wp[layer][ks(8)][nfg(8)][lane(64)][8]
__global__ void k_prepw(const float* __restrict__ ws, const float* __restrict__ wn,
                        unsigned short* __restrict__ wp) {
    int t = blockIdx.x * 256 + threadIdx.x;
    if (t >= 5 * 4096) return;
    int l = t & 63, nfg = (t >> 6) & 7, ks = (t >> 9) & 7, lyr = t >> 12;
    int n = nfg * 16 + (l & 15);
    s16x8 p;
#pragma unroll
    for (int j = 0; j < 8; ++j) {
        int k = ks * 32 + (l >> 4) * 8 + j;
        float v = (k < 128) ? ws[((size_t)lyr * 128 + k) * 128 + n]
                            : wn[((size_t)lyr * 128 + (k - 128)) * 128 + n];
        p[j] = (short)f2bf(v);
    }
    *(s16x8*)&wp[(size_t)t * 8] = p;
}

// pack output-layer W^T fragments: wpo[ks(8)][nf(3)][lane(64)][8], cols >=47 zero
__global__ void k_prepwo(const float* __restrict__ wso, const float* __restrict__ wno,
                         unsigned short* __restrict__ wpo) {
    int t = blockIdx.x * 256 + threadIdx.x;
    if (t >= 1536) return;
    int l = t & 63, q = t >> 6;
    int nf = q % 3, ks = q / 3;
    int n = nf * 16 + (l & 15);
    s16x8 p;
#pragma unroll
    for (int j = 0; j < 8; ++j) {
        int k = ks * 32 + (l >> 4) * 8 + j;
        float v = 0.f;
        if (n < 47) v = (k < 128) ? wso[(size_t)k * 47 + n] : wno[(size_t)(k - 128) * 47 + n];
        p[j] = (short)f2bf(v);
    }
    *(s16x8*)&wpo[(size_t)t * 8] = p;
}

// ---------------- mean aggregation, bf16 (one wave per node) ----------------

__global__ __launch_bounds__(256) void k_agg(const unsigned short* __restrict__ h,
                                             const int* __restrict__ rp,
                                             const int* __restrict__ col,
                                             const float* __restrict__ invd,
                                             unsigned short* __restrict__ out, int n) {
    int gw = (blockIdx.x * 256 + threadIdx.x) >> 6;
    int lane = threadIdx.x & 63;
    if (gw >= n) return;
    const unsigned int* hp = (const unsigned int*)h;
    int beg = rp[gw], end = rp[gw + 1];
    float ax = 0.f, ay = 0.f;
    int e = beg;
    for (; e + 2 <= end; e += 2) {
        int s0 = col[e], s1 = col[e + 1];
        unsigned int v0 = hp[(size_t)s0 * 64 + lane];
        unsigned int v1 = hp[(size_t)s1 * 64 + lane];
        ax += bflo(v0) + bflo(v1);
        ay += bfhi(v0) + bfhi(v1);
    }
    if (e < end) {
        unsigned int v0 = hp[(size_t)col[e] * 64 + lane];
        ax += bflo(v0);
        ay += bfhi(v0);
    }
    float iv = invd[gw];
    unsigned int r = (unsigned int)f2bf(ax * iv) | ((unsigned int)f2bf(ay * iv) << 16);
    ((unsigned int*)out)[(size_t)gw * 64 + lane] = r;
}

// ---------------- fused dual MFMA GEMM: out = relu?(h@Ws + nb@Wn + b) ----------
// 128-row tile, K=256 (h|nb), N=128. 4 waves (2x2), each 64x64 out.
// A staged in LDS in fragment-major order; W pre-packed (W^T frags) in global.

__global__ __launch_bounds__(256) void gemm128(const unsigned short* __restrict__ h,
                                               const unsigned short* __restrict__ nb,
                                               const unsigned short* __restrict__ wl,
                                               const float* __restrict__ bias,
                                               unsigned short* __restrict__ out,
                                               int M, int relu) {
    __shared__ s16x8 afr[4096];  // [ks(8)][mf(8)][lane(64)] : 64 KB
    const int tid = threadIdx.x;
    const int l = tid & 63, w = tid >> 6;
    const int r0 = blockIdx.x * 128;
    const int cg = (w * 4 + (l >> 4)) * 8;  // source col (bf16 elems), granule of 8

    s16x8 th[8], tn[8];
#pragma unroll
    for (int i = 0; i < 8; ++i) {
        int r = r0 + i * 16 + (l & 15);
        if (r >= M) r = M - 1;
        th[i] = *(const s16x8*)(h + (size_t)r * 128 + cg);
        tn[i] = *(const s16x8*)(nb + (size_t)r * 128 + cg);
    }
#pragma unroll
    for (int i = 0; i < 8; ++i) {
        afr[(w * 8 + i) * 64 + l] = th[i];
        afr[((w + 4) * 8 + i) * 64 + l] = tn[i];
    }
    __syncthreads();

    const int mh = w >> 1, nh = w & 1;
    const s16x8* wf = (const s16x8*)wl;

    f32x4 acc[4][4];
#pragma unroll
    for (int i = 0; i < 4; ++i)
#pragma unroll
        for (int j = 0; j < 4; ++j) acc[i][j] = (f32x4)0.f;

#pragma unroll
    for (int ks = 0; ks < 8; ++ks) {
        s16x8 bw[4], ha[4];
#pragma unroll
        for (int nf = 0; nf < 4; ++nf) bw[nf] = wf[(ks * 8 + nh * 4 + nf) * 64 + l];
#pragma unroll
        for (int mf = 0; mf < 4; ++mf) ha[mf] = afr[(ks * 8 + mh * 4 + mf) * 64 + l];
#pragma unroll
        for (int mf = 0; mf < 4; ++mf)
#pragma unroll
            for (int nf = 0; nf < 4; ++nf)
                acc[mf][nf] = __builtin_amdgcn_mfma_f32_16x16x32_bf16(bw[nf], ha[mf],
                                                                      acc[mf][nf], 0, 0, 0);
    }

    // epilogue: lane l owns row (l&15) of each mf-frag, cols (l>>4)*4..+3 of each nf-frag
    f4 bv[4];
#pragma unroll
    for (int nf = 0; nf < 4; ++nf)
        bv[nf] = *(const f4*)&bias[nh * 64 + nf * 16 + ((l >> 4) << 2)];

#pragma unroll
    for (int mf = 0; mf < 4; ++mf) {
        int row = r0 + mh * 64 + mf * 16 + (l & 15);
        if (row >= M) continue;
#pragma unroll
        for (int nf = 0; nf < 4; ++nf) {
            int ncol = nh * 64 + nf * 16 + ((l >> 4) << 2);
            f32x4 a = acc[mf][nf];
            float v0 = a[0] + bv[nf][0], v1 = a[1] + bv[nf][1];
            float v2 = a[2] + bv[nf][2], v3 = a[3] + bv[nf][3];
            if (relu) {
                v0 = fmaxf(v0, 0.f); v1 = fmaxf(v1, 0.f);
                v2 = fmaxf(v2, 0.f); v3 = fmaxf(v3, 0.f);
            }
            uint2 p;
            p.x = (unsigned int)f2bf(v0) | ((unsigned int)f2bf(v1) << 16);
            p.y = (unsigned int)f2bf(v2) | ((unsigned int)f2bf(v3) << 16);
            *(uint2*)(out + (size_t)row * 128 + ncol) = p;
        }
    }
}

// ---------------- final MFMA GEMM 256 -> 47 (f32 out) ----------------

__global__ __launch_bounds__(256) void gemm_out47(const unsigned short* __restrict__ h,
                                                  const unsigned short* __restrict__ nb,
                                                  const unsigned short* __restrict__ wpo,
                                                  const float* __restrict__ bo,
                                                  float* __restrict__ out, int M) {
    __shared__ s16x8 afr[4096];
    const int tid = threadIdx.x;
    const int l = tid & 63, w = tid >> 6;
    const int r0 = blockIdx.x * 128;
    const int cg = (w * 4 + (l >> 4)) * 8;

    s16x8 th[8], tn[8];
#pragma unroll
    for (int i = 0; i < 8; ++i) {
        int r = r0 + i * 16 + (l & 15);
        if (r >= M) r = M - 1;
        th[i] = *(const s16x8*)(h + (size_t)r * 128 + cg);
        tn[i] = *(const s16x8*)(nb + (size_t)r * 128 + cg);
    }
#pragma unroll
    for (int i = 0; i < 8; ++i) {
        afr[(w * 8 + i) * 64 + l] = th[i];
        afr[((w + 4) * 8 + i) * 64 + l] = tn[i];
    }
    __syncthreads();

    const s16x8* wf = (const s16x8*)wpo;
    f32x4 acc[2][3];
#pragma unroll
    for (int i = 0; i < 2; ++i)
#pragma unroll
        for (int j = 0; j < 3; ++j) acc[i][j] = (f32x4)0.f;

#pragma unroll
    for (int ks = 0; ks < 8; ++ks) {
        s16x8 bw[3], ha[2];
#pragma unroll
        for (int nf = 0; nf < 3; ++nf) bw[nf] = wf[(ks * 3 + nf) * 64 + l];
#pragma unroll
        for (int mf = 0; mf < 2; ++mf) ha[mf] = afr[(ks * 8 + w * 2 + mf) * 64 + l];
#pragma unroll
        for (int mf = 0; mf < 2; ++mf)
#pragma unroll
            for (int nf = 0; nf < 3; ++nf)
                acc[mf][nf] = __builtin_amdgcn_mfma_f32_16x16x32_bf16(bw[nf], ha[mf],
                                                                      acc[mf][nf], 0, 0, 0);
    }

#pragma unroll
    for (int mf = 0; mf < 2; ++mf) {
        int row = r0 + w * 32 + mf * 16 + (l & 15);
        if (row >= M) continue;
#pragma unroll
        for (int nf = 0; nf < 3; ++nf) {
            int ncol = nf * 16 + ((l >> 4) << 2);
            f32x4 a = acc[mf][nf];
#pragma unroll
            for (int jj = 0; jj < 4; ++jj) {
                int n = ncol + jj;
                if (n < 47) out[(size_t)row * 47 + n] = a[jj] + bo[n];
            }
        }
    }
}

// ---------------- launch ----------------

static inline char* alignp(char* p) {
    return (char*)(((size_t)p + 255) & ~(size_t)255);
}

extern "C" void kernel_launch(void* const* d_in, const int* in_sizes, int n_in,
                              void* d_out, int out_size, void* d_ws, size_t ws_size,
                              hipStream_t stream) {
    const float* x = (const float*)d_in[0];
    const int* src = (const int*)d_in[1];
    const int* dst = (const int*)d_in[2];
    const float* w_self = (const float*)d_in[3];
    const float* w_neigh = (const float*)d_in[4];
    const float* b = (const float*)d_in[5];
    const float* wso = (const float*)d_in[6];
    const float* wno = (const float*)d_in[7];
    const float* bo = (const float*)d_in[8];
    float* out = (float*)d_out;

    const int N = N_NODES;
    const int E = in_sizes[1];

    char* w = (char*)d_ws;
    unsigned short* xb = (unsigned short*)w;  w = alignp(w + (size_t)N * 128 * 2);
    unsigned short* hA = (unsigned short*)w;  w = alignp(w + (size_t)N * 128 * 2);
    unsigned short* hB = (unsigned short*)w;  w = alignp(w + (size_t)N * 128 * 2);
    unsigned short* wp = (unsigned short*)w;  w = alignp(w + (size_t)5 * 32768 * 2);
    unsigned short* wpo = (unsigned short*)w; w = alignp(w + (size_t)1536 * 8 * 2);
    int* deg = (int*)w;      w = alignp(w + (size_t)N * 4);
    int* rp = (int*)w;       w = alignp(w + (size_t)(N + 4) * 4);
    int* cnt = (int*)w;      w = alignp(w + (size_t)N * 4);
    int* col = (int*)w;      w = alignp(w + (size_t)E * 4);
    int* bsum = (int*)w;     w = alignp(w + 4096);
    float* invd = (float*)w; w = alignp(w + (size_t)N * 4);

    hipMemsetAsync(deg, 0, (size_t)N * 4, stream);
    hipMemsetAsync(cnt, 0, (size_t)N * 4, stream);

    int eb = (E + 255) / 256;
    int nblk = (N + 255) / 256;  // 391
    k_count<<<eb, 256, 0, stream>>>(dst, deg, E);
    k_scan1<<<nblk, 256, 0, stream>>>(deg, rp, bsum, N);
    k_scan2<<<1, 512, 0, stream>>>(bsum, nblk);
    k_fin<<<nblk, 256, 0, stream>>>(deg, rp, bsum, invd, N, E);
    k_scatter<<<eb, 256, 0, stream>>>(src, dst, rp, cnt, col, E);

    k_cvt<<<(N * 128 / 8 + 255) / 256, 256, 0, stream>>>(x, xb, N * 128 / 8);
    k_prepw<<<(5 * 4096 + 255) / 256, 256, 0, stream>>>(w_self, w_neigh, wp);
    k_prepwo<<<6, 256, 0, stream>>>(wso, wno, wpo);

    const int aggBlocks = (N * 64 + 255) / 256;   // 25000
    const int gemmBlocks = (N + 127) / 128;       // 782

    // layer 0 (no relu): agg(xb)->hA, gemm writes in-place into hA
    k_agg<<<aggBlocks, 256, 0, stream>>>(xb, rp, col, invd, hA, N);
    gemm128<<<gemmBlocks, 256, 0, stream>>>(xb, hA, wp, b, hA, N, 0);

    unsigned short* cur = hA;
    unsigned short* oth = hB;
    for (int lyr = 1; lyr < 5; ++lyr) {
        k_agg<<<aggBlocks, 256, 0, stream>>>(cur, rp, col, invd, oth, N);
        gemm128<<<gemmBlocks, 256, 0, stream>>>(cur, oth, wp + (size_t)lyr * 32768,
                                                b + (size_t)lyr * 128, oth, N, 1);
        unsigned short* t = cur; cur = oth; oth = t;
    }

    k_agg<<<aggBlocks, 256, 0, stream>>>(cur, rp, col, invd, oth, N);
    gemm_out47<<<gemmBlocks, 256, 0, stream>>>(cur, oth, wpo, bo, out, N);
}

// Round 3
// 580.331 us; speedup vs baseline: 3.2903x; 1.5749x over previous
//
#include <hip/hip_runtime.h>

typedef float f4 __attribute__((ext_vector_type(4)));
typedef float f32x4 __attribute__((ext_vector_type(4)));
typedef short s16x8 __attribute__((ext_vector_type(8)));

#define N_NODES 100000
#define NBUCK 196   // ceil(100000/512)
#define NB1 256     // blocks in hist/place passes

__device__ inline unsigned short f2bf(float f) {
    unsigned int u = __builtin_bit_cast(unsigned int, f);
    u += 0x7FFFu + ((u >> 16) & 1u);
    return (unsigned short)(u >> 16);
}
__device__ inline float bflo(unsigned int v) { return __builtin_bit_cast(float, v << 16); }
__device__ inline float bfhi(unsigned int v) { return __builtin_bit_cast(float, v & 0xFFFF0000u); }

// ---------------- bucketed CSR build ----------------
// bucket = dst >> 9 (512 nodes per bucket); edge packed as src | (dst&511)<<17

__global__ __launch_bounds__(256) void k_hist(const int* __restrict__ dst,
                                              int* __restrict__ histG, int E) {
    __shared__ int h[NBUCK];
    int tid = threadIdx.x;
    for (int i = tid; i < NBUCK; i += 256) h[i] = 0;
    __syncthreads();
    int chunk = (E + NB1 - 1) / NB1;
    int s = blockIdx.x * chunk, eN = min(E, s + chunk);
    for (int i = s + tid; i < eN; i += 256) atomicAdd(&h[dst[i] >> 9], 1);
    __syncthreads();
    for (int i = tid; i < NBUCK; i += 256) histG[i * NB1 + blockIdx.x] = h[i];
}

// exclusive scan of histG[NBUCK*NB1] (bucket-major), 1 block x 1024 thr, 49 each
__global__ __launch_bounds__(1024) void k_scanB(int* __restrict__ histG) {
    __shared__ int ps[1024];
    int t = threadIdx.x;
    int base = t * 49;
    int vals[49];
    int sum = 0;
#pragma unroll
    for (int i = 0; i < 49; ++i) { vals[i] = histG[base + i]; sum += vals[i]; }
    ps[t] = sum;
    __syncthreads();
    for (int off = 1; off < 1024; off <<= 1) {
        int v = (t >= off) ? ps[t - off] : 0;
        __syncthreads();
        ps[t] += v;
        __syncthreads();
    }
    int run = ps[t] - sum;  // exclusive prefix of this thread's chunk
#pragma unroll
    for (int i = 0; i < 49; ++i) { int v = vals[i]; histG[base + i] = run; run += v; }
}

__global__ __launch_bounds__(256) void k_place(const int* __restrict__ src,
                                               const int* __restrict__ dst,
                                               const int* __restrict__ histG,
                                               unsigned int* __restrict__ ebuf, int E) {
    __shared__ int cur[NBUCK];
    int tid = threadIdx.x;
    for (int i = tid; i < NBUCK; i += 256) cur[i] = histG[i * NB1 + blockIdx.x];
    __syncthreads();
    int chunk = (E + NB1 - 1) / NB1;
    int s = blockIdx.x * chunk, eN = min(E, s + chunk);
    for (int i = s + tid; i < eN; i += 256) {
        int d = dst[i];
        int b = d >> 9;
        int pos = atomicAdd(&cur[b], 1);
        ebuf[pos] = (unsigned int)src[i] | ((unsigned int)(d & 511) << 17);
    }
}

// one block per bucket: LDS degree count + scan, then L2-local col scatter
__global__ __launch_bounds__(256) void k_csr(const unsigned int* __restrict__ ebuf,
                                             const int* __restrict__ histG,
                                             int* __restrict__ rp, int* __restrict__ col,
                                             float* __restrict__ invd, int N, int E) {
    __shared__ int ldeg[512];
    __shared__ int lbase[512];
    int b = blockIdx.x, tid = threadIdx.x;
    int base = histG[b * NB1];
    int endB = (b == NBUCK - 1) ? E : histG[(b + 1) * NB1];
    int cnt = endB - base;
    int n0 = b << 9;

    ldeg[tid] = 0;
    ldeg[tid + 256] = 0;
    __syncthreads();
    for (int i = tid; i < cnt; i += 256) atomicAdd(&ldeg[ebuf[base + i] >> 17], 1);
    __syncthreads();

    int a0 = ldeg[tid], a1 = ldeg[tid + 256];
    lbase[tid] = a0;
    lbase[tid + 256] = a1;
    __syncthreads();
    for (int off = 1; off < 512; off <<= 1) {
        int v0 = (tid >= off) ? lbase[tid - off] : 0;
        int v1 = (tid + 256 >= off) ? lbase[tid + 256 - off] : 0;
        __syncthreads();
        lbase[tid] += v0;
        lbase[tid + 256] += v1;
        __syncthreads();
    }
    int e0 = lbase[tid] - a0, e1 = lbase[tid + 256] - a1;  // exclusive
    __syncthreads();
    lbase[tid] = e0;
    lbase[tid + 256] = e1;
    // reset ldeg as cursors
    ldeg[tid] = 0;
    ldeg[tid + 256] = 0;
    __syncthreads();

    for (int i = tid; i < cnt; i += 256) {
        unsigned int p = ebuf[base + i];
        int dl = p >> 17;
        int pos = base + lbase[dl] + atomicAdd(&ldeg[dl], 1);
        col[pos] = (int)(p & 0x1FFFFu);
    }

    int g0 = n0 + tid, g1 = n0 + tid + 256;
    if (g0 < N) { rp[g0] = base + e0; invd[g0] = 1.0f / fmaxf((float)a0, 1.0f); }
    if (g1 < N) { rp[g1] = base + e1; invd[g1] = 1.0f / fmaxf((float)a1, 1.0f); }
    if (b == NBUCK - 1 && tid == 0) rp[N] = E;
}

// ---------------- prep: f32 -> bf16 conversions / weight packing ----------------

__global__ void k_cvt(const float* __restrict__ x, unsigned short* __restrict__ xb, int n8) {
    int t = blockIdx.x * 256 + threadIdx.x;
    if (t >= n8) return;
    f4 a = *(const f4*)&x[(size_t)t * 8];
    f4 b = *(const f4*)&x[(size_t)t * 8 + 4];
    s16x8 p;
    p[0] = (short)f2bf(a[0]); p[1] = (short)f2bf(a[1]);
    p[2] = (short)f2bf(a[2]); p[3] = (short)f2bf(a[3]);
    p[4] = (short)f2bf(b[0]); p[5] = (short)f2bf(b[1]);
    p[6] = (short)f2bf(b[2]); p[7] = (short)f2bf(b[3]);
    *(s16x8*)&xb[(size_t)t * 8] = p;
}

// pack W^T fragments: wp[layer][ks(8)][nfg(8)][lane(64)][8]
__global__ void k_prepw(const float* __restrict__ ws, const float* __restrict__ wn,
                        unsigned short* __restrict__ wp) {
    int t = blockIdx.x * 256 + threadIdx.x;
    if (t >= 5 * 4096) return;
    int l = t & 63, nfg = (t >> 6) & 7, ks = (t >> 9) & 7, lyr = t >> 12;
    int n = nfg * 16 + (l & 15);
    s16x8 p;
#pragma unroll
    for (int j = 0; j < 8; ++j) {
        int k = ks * 32 + (l >> 4) * 8 + j;
        float v = (k < 128) ? ws[((size_t)lyr * 128 + k) * 128 + n]
                            : wn[((size_t)lyr * 128 + (k - 128)) * 128 + n];
        p[j] = (short)f2bf(v);
    }
    *(s16x8*)&wp[(size_t)t * 8] = p;
}

// pack output-layer W^T fragments: wpo[ks(8)][nf(3)][lane(64)][8], cols >=47 zero
__global__ void k_prepwo(const float* __restrict__ wso, const float* __restrict__ wno,
                         unsigned short* __restrict__ wpo) {
    int t = blockIdx.x * 256 + threadIdx.x;
    if (t >= 1536) return;
    int l = t & 63, q = t >> 6;
    int nf = q % 3, ks = q / 3;
    int n = nf * 16 + (l & 15);
    s16x8 p;
#pragma unroll
    for (int j = 0; j < 8; ++j) {
        int k = ks * 32 + (l >> 4) * 8 + j;
        float v = 0.f;
        if (n < 47) v = (k < 128) ? wso[(size_t)k * 47 + n] : wno[(size_t)(k - 128) * 47 + n];
        p[j] = (short)f2bf(v);
    }
    *(s16x8*)&wpo[(size_t)t * 8] = p;
}

// ---------------- mean aggregation, bf16, unroll-8 for MLP ----------------

__global__ __launch_bounds__(256) void k_agg(const unsigned short* __restrict__ h,
                                             const int* __restrict__ rp,
                                             const int* __restrict__ col,
                                             const float* __restrict__ invd,
                                             unsigned short* __restrict__ out, int n) {
    int gw = (blockIdx.x * 256 + threadIdx.x) >> 6;
    int lane = threadIdx.x & 63;
    if (gw >= n) return;
    const unsigned int* hp = (const unsigned int*)h;
    int beg = rp[gw], end = rp[gw + 1];
    float ax = 0.f, ay = 0.f;
    int e = beg;
    for (; e + 8 <= end; e += 8) {
        unsigned int u[8];
#pragma unroll
        for (int i = 0; i < 8; ++i) u[i] = hp[(size_t)col[e + i] * 64 + lane];
#pragma unroll
        for (int i = 0; i < 8; ++i) { ax += bflo(u[i]); ay += bfhi(u[i]); }
    }
    if (e < end) {
        int rem = end - e;
        unsigned int u[8];
#pragma unroll
        for (int i = 0; i < 8; ++i) {
            int idx = (i < rem) ? (e + i) : e;
            u[i] = hp[(size_t)col[idx] * 64 + lane];
        }
#pragma unroll
        for (int i = 0; i < 8; ++i) {
            if (i < rem) { ax += bflo(u[i]); ay += bfhi(u[i]); }
        }
    }
    float iv = invd[gw];
    unsigned int r = (unsigned int)f2bf(ax * iv) | ((unsigned int)f2bf(ay * iv) << 16);
    ((unsigned int*)out)[(size_t)gw * 64 + lane] = r;
}

// ---------------- fused dual MFMA GEMM: out = relu?(h@Ws + nb@Wn + b) ----------

__global__ __launch_bounds__(256) void gemm128(const unsigned short* __restrict__ h,
                                               const unsigned short* __restrict__ nb,
                                               const unsigned short* __restrict__ wl,
                                               const float* __restrict__ bias,
                                               unsigned short* __restrict__ out,
                                               int M, int relu) {
    __shared__ s16x8 afr[4096];  // [ks(8)][mf(8)][lane(64)] : 64 KB
    const int tid = threadIdx.x;
    const int l = tid & 63, w = tid >> 6;
    const int r0 = blockIdx.x * 128;
    const int cg = (w * 4 + (l >> 4)) * 8;

    s16x8 th[8], tn[8];
#pragma unroll
    for (int i = 0; i < 8; ++i) {
        int r = r0 + i * 16 + (l & 15);
        if (r >= M) r = M - 1;
        th[i] = *(const s16x8*)(h + (size_t)r * 128 + cg);
        tn[i] = *(const s16x8*)(nb + (size_t)r * 128 + cg);
    }
#pragma unroll
    for (int i = 0; i < 8; ++i) {
        afr[(w * 8 + i) * 64 + l] = th[i];
        afr[((w + 4) * 8 + i) * 64 + l] = tn[i];
    }
    __syncthreads();

    const int mh = w >> 1, nh = w & 1;
    const s16x8* wf = (const s16x8*)wl;

    f32x4 acc[4][4];
#pragma unroll
    for (int i = 0; i < 4; ++i)
#pragma unroll
        for (int j = 0; j < 4; ++j) acc[i][j] = (f32x4)0.f;

#pragma unroll
    for (int ks = 0; ks < 8; ++ks) {
        s16x8 bw[4], ha[4];
#pragma unroll
        for (int nf = 0; nf < 4; ++nf) bw[nf] = wf[(ks * 8 + nh * 4 + nf) * 64 + l];
#pragma unroll
        for (int mf = 0; mf < 4; ++mf) ha[mf] = afr[(ks * 8 + mh * 4 + mf) * 64 + l];
#pragma unroll
        for (int mf = 0; mf < 4; ++mf)
#pragma unroll
            for (int nf = 0; nf < 4; ++nf)
                acc[mf][nf] = __builtin_amdgcn_mfma_f32_16x16x32_bf16(bw[nf], ha[mf],
                                                                      acc[mf][nf], 0, 0, 0);
    }

    f4 bv[4];
#pragma unroll
    for (int nf = 0; nf < 4; ++nf)
        bv[nf] = *(const f4*)&bias[nh * 64 + nf * 16 + ((l >> 4) << 2)];

#pragma unroll
    for (int mf = 0; mf < 4; ++mf) {
        int row = r0 + mh * 64 + mf * 16 + (l & 15);
        if (row >= M) continue;
#pragma unroll
        for (int nf = 0; nf < 4; ++nf) {
            int ncol = nh * 64 + nf * 16 + ((l >> 4) << 2);
            f32x4 a = acc[mf][nf];
            float v0 = a[0] + bv[nf][0], v1 = a[1] + bv[nf][1];
            float v2 = a[2] + bv[nf][2], v3 = a[3] + bv[nf][3];
            if (relu) {
                v0 = fmaxf(v0, 0.f); v1 = fmaxf(v1, 0.f);
                v2 = fmaxf(v2, 0.f); v3 = fmaxf(v3, 0.f);
            }
            uint2 p;
            p.x = (unsigned int)f2bf(v0) | ((unsigned int)f2bf(v1) << 16);
            p.y = (unsigned int)f2bf(v2) | ((unsigned int)f2bf(v3) << 16);
            *(uint2*)(out + (size_t)row * 128 + ncol) = p;
        }
    }
}

// ---------------- final MFMA GEMM 256 -> 47 (f32 out) ----------------

__global__ __launch_bounds__(256) void gemm_out47(const unsigned short* __restrict__ h,
                                                  const unsigned short* __restrict__ nb,
                                                  const unsigned short* __restrict__ wpo,
                                                  const float* __restrict__ bo,
                                                  float* __restrict__ out, int M) {
    __shared__ s16x8 afr[4096];
    const int tid = threadIdx.x;
    const int l = tid & 63, w = tid >> 6;
    const int r0 = blockIdx.x * 128;
    const int cg = (w * 4 + (l >> 4)) * 8;

    s16x8 th[8], tn[8];
#pragma unroll
    for (int i = 0; i < 8; ++i) {
        int r = r0 + i * 16 + (l & 15);
        if (r >= M) r = M - 1;
        th[i] = *(const s16x8*)(h + (size_t)r * 128 + cg);
        tn[i] = *(const s16x8*)(nb + (size_t)r * 128 + cg);
    }
#pragma unroll
    for (int i = 0; i < 8; ++i) {
        afr[(w * 8 + i) * 64 + l] = th[i];
        afr[((w + 4) * 8 + i) * 64 + l] = tn[i];
    }
    __syncthreads();

    const s16x8* wf = (const s16x8*)wpo;
    f32x4 acc[2][3];
#pragma unroll
    for (int i = 0; i < 2; ++i)
#pragma unroll
        for (int j = 0; j < 3; ++j) acc[i][j] = (f32x4)0.f;

#pragma unroll
    for (int ks = 0; ks < 8; ++ks) {
        s16x8 bw[3], ha[2];
#pragma unroll
        for (int nf = 0; nf < 3; ++nf) bw[nf] = wf[(ks * 3 + nf) * 64 + l];
#pragma unroll
        for (int mf = 0; mf < 2; ++mf) ha[mf] = afr[(ks * 8 + w * 2 + mf) * 64 + l];
#pragma unroll
        for (int mf = 0; mf < 2; ++mf)
#pragma unroll
            for (int nf = 0; nf < 3; ++nf)
                acc[mf][nf] = __builtin_amdgcn_mfma_f32_16x16x32_bf16(bw[nf], ha[mf],
                                                                      acc[mf][nf], 0, 0, 0);
    }

#pragma unroll
    for (int mf = 0; mf < 2; ++mf) {
        int row = r0 + w * 32 + mf * 16 + (l & 15);
        if (row >= M) continue;
#pragma unroll
        for (int nf = 0; nf < 3; ++nf) {
            int ncol = nf * 16 + ((l >> 4) << 2);
            f32x4 a = acc[mf][nf];
#pragma unroll
            for (int jj = 0; jj < 4; ++jj) {
                int n = ncol + jj;
                if (n < 47) out[(size_t)row * 47 + n] = a[jj] + bo[n];
            }
        }
    }
}

// ---------------- launch ----------------

static inline char* alignp(char* p) {
    return (char*)(((size_t)p + 255) & ~(size_t)255);
}

extern "C" void kernel_launch(void* const* d_in, const int* in_sizes, int n_in,
                              void* d_out, int out_size, void* d_ws, size_t ws_size,
                              hipStream_t stream) {
    const float* x = (const float*)d_in[0];
    const int* src = (const int*)d_in[1];
    const int* dst = (const int*)d_in[2];
    const float* w_self = (const float*)d_in[3];
    const float* w_neigh = (const float*)d_in[4];
    const float* b = (const float*)d_in[5];
    const float* wso = (const float*)d_in[6];
    const float* wno = (const float*)d_in[7];
    const float* bo = (const float*)d_in[8];
    float* out = (float*)d_out;

    const int N = N_NODES;
    const int E = in_sizes[1];

    char* w = (char*)d_ws;
    unsigned short* xb = (unsigned short*)w;  w = alignp(w + (size_t)N * 128 * 2);
    unsigned short* hA = (unsigned short*)w;  w = alignp(w + (size_t)N * 128 * 2);
    unsigned short* hB = (unsigned short*)w;  w = alignp(w + (size_t)N * 128 * 2);
    unsigned short* wp = (unsigned short*)w;  w = alignp(w + (size_t)5 * 32768 * 2);
    unsigned short* wpo = (unsigned short*)w; w = alignp(w + (size_t)1536 * 8 * 2);
    int* rp = (int*)w;       w = alignp(w + (size_t)(N + 4) * 4);
    int* col = (int*)w;      w = alignp(w + (size_t)E * 4);
    int* histG = (int*)w;    w = alignp(w + (size_t)NBUCK * NB1 * 4);
    float* invd = (float*)w; w = alignp(w + (size_t)N * 4);

    // ebuf (packed edges, E*4 bytes) aliases hB: hB is first touched at layer-1
    // aggregation, long after k_csr has consumed ebuf.
    unsigned int* ebuf = (unsigned int*)hB;

    // CSR build (bucketed, L2-local scatters)
    k_hist<<<NB1, 256, 0, stream>>>(dst, histG, E);
    k_scanB<<<1, 1024, 0, stream>>>(histG);
    k_place<<<NB1, 256, 0, stream>>>(src, dst, histG, ebuf, E);
    k_csr<<<NBUCK, 256, 0, stream>>>(ebuf, histG, rp, col, invd, N, E);

    // dtype prep
    k_cvt<<<(N * 128 / 8 + 255) / 256, 256, 0, stream>>>(x, xb, N * 128 / 8);
    k_prepw<<<(5 * 4096 + 255) / 256, 256, 0, stream>>>(w_self, w_neigh, wp);
    k_prepwo<<<6, 256, 0, stream>>>(wso, wno, wpo);

    const int aggBlocks = (N * 64 + 255) / 256;   // 25000
    const int gemmBlocks = (N + 127) / 128;       // 782

    // layer 0 (no relu): agg(xb)->hA, gemm writes in-place into hA
    k_agg<<<aggBlocks, 256, 0, stream>>>(xb, rp, col, invd, hA, N);
    gemm128<<<gemmBlocks, 256, 0, stream>>>(xb, hA, wp, b, hA, N, 0);

    unsigned short* cur = hA;
    unsigned short* oth = hB;
    for (int lyr = 1; lyr < 5; ++lyr) {
        k_agg<<<aggBlocks, 256, 0, stream>>>(cur, rp, col, invd, oth, N);
        gemm128<<<gemmBlocks, 256, 0, stream>>>(cur, oth, wp + (size_t)lyr * 32768,
                                                b + (size_t)lyr * 128, oth, N, 1);
        unsigned short* t = cur; cur = oth; oth = t;
    }

    k_agg<<<aggBlocks, 256, 0, stream>>>(cur, rp, col, invd, oth, N);
    gemm_out47<<<gemmBlocks, 256, 0, stream>>>(cur, oth, wpo, bo, out, N);
}

// Round 4
// 578.843 us; speedup vs baseline: 3.2987x; 1.0026x over previous
//
#include <hip/hip_runtime.h>

typedef float f4 __attribute__((ext_vector_type(4)));
typedef float f32x4 __attribute__((ext_vector_type(4)));
typedef float f2 __attribute__((ext_vector_type(2)));
typedef short s16x8 __attribute__((ext_vector_type(8)));
typedef int i4 __attribute__((ext_vector_type(4)));

#define N_NODES 100000
#define NBUCK 196   // ceil(100000/512)
#define NB1 256     // blocks in hist/place passes

__device__ inline unsigned short f2bf(float f) {
    unsigned int u = __builtin_bit_cast(unsigned int, f);
    u += 0x7FFFu + ((u >> 16) & 1u);
    return (unsigned short)(u >> 16);
}
__device__ inline float bflo(unsigned int v) { return __builtin_bit_cast(float, v << 16); }
__device__ inline float bfhi(unsigned int v) { return __builtin_bit_cast(float, v & 0xFFFF0000u); }

// ---------------- bucketed CSR build ----------------
// bucket = dst >> 9 (512 nodes per bucket); edge packed as src | (dst&511)<<17

__global__ __launch_bounds__(256) void k_hist(const int* __restrict__ dst,
                                              int* __restrict__ histG, int E) {
    __shared__ int h[NBUCK];
    int tid = threadIdx.x;
    for (int i = tid; i < NBUCK; i += 256) h[i] = 0;
    __syncthreads();
    int chunk = (E + NB1 - 1) / NB1;
    int s = blockIdx.x * chunk, eN = min(E, s + chunk);
    for (int i = s + tid; i < eN; i += 256) atomicAdd(&h[dst[i] >> 9], 1);
    __syncthreads();
    for (int i = tid; i < NBUCK; i += 256) histG[i * NB1 + blockIdx.x] = h[i];
}

// exclusive scan of histG[NBUCK*NB1] (bucket-major), 1 block x 1024 thr, 49 each
__global__ __launch_bounds__(1024) void k_scanB(int* __restrict__ histG) {
    __shared__ int ps[1024];
    int t = threadIdx.x;
    int base = t * 49;
    int vals[49];
    int sum = 0;
#pragma unroll
    for (int i = 0; i < 49; ++i) { vals[i] = histG[base + i]; sum += vals[i]; }
    ps[t] = sum;
    __syncthreads();
    for (int off = 1; off < 1024; off <<= 1) {
        int v = (t >= off) ? ps[t - off] : 0;
        __syncthreads();
        ps[t] += v;
        __syncthreads();
    }
    int run = ps[t] - sum;  // exclusive prefix of this thread's chunk
#pragma unroll
    for (int i = 0; i < 49; ++i) { int v = vals[i]; histG[base + i] = run; run += v; }
}

__global__ __launch_bounds__(256) void k_place(const int* __restrict__ src,
                                               const int* __restrict__ dst,
                                               const int* __restrict__ histG,
                                               unsigned int* __restrict__ ebuf, int E) {
    __shared__ int cur[NBUCK];
    int tid = threadIdx.x;
    for (int i = tid; i < NBUCK; i += 256) cur[i] = histG[i * NB1 + blockIdx.x];
    __syncthreads();
    int chunk = (E + NB1 - 1) / NB1;
    int s = blockIdx.x * chunk, eN = min(E, s + chunk);
    for (int i = s + tid; i < eN; i += 256) {
        int d = dst[i];
        int b = d >> 9;
        int pos = atomicAdd(&cur[b], 1);
        ebuf[pos] = (unsigned int)src[i] | ((unsigned int)(d & 511) << 17);
    }
}

// one block per bucket: LDS degree count + scan, then L2-local col scatter.
// col is stored as BYTE offsets (src*256) for the bf16 row gather.
__global__ __launch_bounds__(256) void k_csr(const unsigned int* __restrict__ ebuf,
                                             const int* __restrict__ histG,
                                             int* __restrict__ rp, int* __restrict__ col,
                                             float* __restrict__ invd, int N, int E) {
    __shared__ int ldeg[512];
    __shared__ int lbase[512];
    int b = blockIdx.x, tid = threadIdx.x;
    int base = histG[b * NB1];
    int endB = (b == NBUCK - 1) ? E : histG[(b + 1) * NB1];
    int cnt = endB - base;
    int n0 = b << 9;

    ldeg[tid] = 0;
    ldeg[tid + 256] = 0;
    __syncthreads();
    for (int i = tid; i < cnt; i += 256) atomicAdd(&ldeg[ebuf[base + i] >> 17], 1);
    __syncthreads();

    int a0 = ldeg[tid], a1 = ldeg[tid + 256];
    lbase[tid] = a0;
    lbase[tid + 256] = a1;
    __syncthreads();
    for (int off = 1; off < 512; off <<= 1) {
        int v0 = (tid >= off) ? lbase[tid - off] : 0;
        int v1 = (tid + 256 >= off) ? lbase[tid + 256 - off] : 0;
        __syncthreads();
        lbase[tid] += v0;
        lbase[tid + 256] += v1;
        __syncthreads();
    }
    int e0 = lbase[tid] - a0, e1 = lbase[tid + 256] - a1;  // exclusive
    __syncthreads();
    lbase[tid] = e0;
    lbase[tid + 256] = e1;
    ldeg[tid] = 0;
    ldeg[tid + 256] = 0;
    __syncthreads();

    for (int i = tid; i < cnt; i += 256) {
        unsigned int p = ebuf[base + i];
        int dl = p >> 17;
        int pos = base + lbase[dl] + atomicAdd(&ldeg[dl], 1);
        col[pos] = (int)(p & 0x1FFFFu) << 8;   // byte offset into bf16 row table
    }

    int g0 = n0 + tid, g1 = n0 + tid + 256;
    if (g0 < N) { rp[g0] = base + e0; invd[g0] = 1.0f / fmaxf((float)a0, 1.0f); }
    if (g1 < N) { rp[g1] = base + e1; invd[g1] = 1.0f / fmaxf((float)a1, 1.0f); }
    if (b == NBUCK - 1 && tid == 0) rp[N] = E;
}

// ---------------- prep: f32 -> bf16 conversions / weight packing ----------------

__global__ void k_cvt(const float* __restrict__ x, unsigned short* __restrict__ xb, int n8) {
    int t = blockIdx.x * 256 + threadIdx.x;
    if (t >= n8) return;
    f4 a = *(const f4*)&x[(size_t)t * 8];
    f4 b = *(const f4*)&x[(size_t)t * 8 + 4];
    s16x8 p;
    p[0] = (short)f2bf(a[0]); p[1] = (short)f2bf(a[1]);
    p[2] = (short)f2bf(a[2]); p[3] = (short)f2bf(a[3]);
    p[4] = (short)f2bf(b[0]); p[5] = (short)f2bf(b[1]);
    p[6] = (short)f2bf(b[2]); p[7] = (short)f2bf(b[3]);
    *(s16x8*)&xb[(size_t)t * 8] = p;
}

// pack W^T fragments: wp[layer][ks(8)][nfg(8)][lane(64)][8]
__global__ void k_prepw(const float* __restrict__ ws, const float* __restrict__ wn,
                        unsigned short* __restrict__ wp) {
    int t = blockIdx.x * 256 + threadIdx.x;
    if (t >= 5 * 4096) return;
    int l = t & 63, nfg = (t >> 6) & 7, ks = (t >> 9) & 7, lyr = t >> 12;
    int n = nfg * 16 + (l & 15);
    s16x8 p;
#pragma unroll
    for (int j = 0; j < 8; ++j) {
        int k = ks * 32 + (l >> 4) * 8 + j;
        float v = (k < 128) ? ws[((size_t)lyr * 128 + k) * 128 + n]
                            : wn[((size_t)lyr * 128 + (k - 128)) * 128 + n];
        p[j] = (short)f2bf(v);
    }
    *(s16x8*)&wp[(size_t)t * 8] = p;
}

// pack output-layer W^T fragments: wpo[ks(8)][nf(3)][lane(64)][8], cols >=47 zero
__global__ void k_prepwo(const float* __restrict__ wso, const float* __restrict__ wno,
                         unsigned short* __restrict__ wpo) {
    int t = blockIdx.x * 256 + threadIdx.x;
    if (t >= 1536) return;
    int l = t & 63, q = t >> 6;
    int nf = q % 3, ks = q / 3;
    int n = nf * 16 + (l & 15);
    s16x8 p;
#pragma unroll
    for (int j = 0; j < 8; ++j) {
        int k = ks * 32 + (l >> 4) * 8 + j;
        float v = 0.f;
        if (n < 47) v = (k < 128) ? wso[(size_t)k * 47 + n] : wno[(size_t)(k - 128) * 47 + n];
        p[j] = (short)f2bf(v);
    }
    *(s16x8*)&wpo[(size_t)t * 8] = p;
}

// ---------------- mean aggregation, bf16 ----------------
// col holds byte offsets; gathers use uniform-base + 32-bit voffset (saddr form).
// Accumulate as float2 -> v_pk_add_f32.

__global__ __launch_bounds__(256) void k_agg(const unsigned short* __restrict__ h,
                                             const int* __restrict__ rp,
                                             const int* __restrict__ col,
                                             const float* __restrict__ invd,
                                             unsigned short* __restrict__ out, int n) {
    int gw = (blockIdx.x * 256 + threadIdx.x) >> 6;
    int lane = threadIdx.x & 63;
    if (gw >= n) return;
    const char* hb = (const char*)h;
    const int lb = lane * 4;
    int beg = rp[gw], end = rp[gw + 1];
    f2 acc = {0.f, 0.f};
    int e = beg;
    for (; e + 8 <= end; e += 8) {
        i4 c0, c1;
        __builtin_memcpy(&c0, &col[e], 16);
        __builtin_memcpy(&c1, &col[e + 4], 16);
        unsigned int u[8];
#pragma unroll
        for (int i = 0; i < 4; ++i)
            u[i] = *(const unsigned int*)(hb + (unsigned int)(c0[i] + lb));
#pragma unroll
        for (int i = 0; i < 4; ++i)
            u[4 + i] = *(const unsigned int*)(hb + (unsigned int)(c1[i] + lb));
#pragma unroll
        for (int i = 0; i < 8; ++i) {
            f2 v = {bflo(u[i]), bfhi(u[i])};
            acc += v;
        }
    }
    if (e < end) {
        int rem = end - e;
        // over-read stays inside the workspace; garbage offsets are <= E and
        // therefore still valid byte offsets into the 25.6 MB row table.
        i4 c0, c1;
        __builtin_memcpy(&c0, &col[e], 16);
        __builtin_memcpy(&c1, &col[e + 4], 16);
        unsigned int u[8];
#pragma unroll
        for (int i = 0; i < 4; ++i)
            u[i] = *(const unsigned int*)(hb + (unsigned int)(c0[i] + lb));
#pragma unroll
        for (int i = 0; i < 4; ++i)
            u[4 + i] = *(const unsigned int*)(hb + (unsigned int)(c1[i] + lb));
#pragma unroll
        for (int i = 0; i < 8; ++i) {
            if (i < rem) {  // rem is wave-uniform
                f2 v = {bflo(u[i]), bfhi(u[i])};
                acc += v;
            }
        }
    }
    float iv = invd[gw];
    unsigned int r = (unsigned int)f2bf(acc[0] * iv) | ((unsigned int)f2bf(acc[1] * iv) << 16);
    ((unsigned int*)out)[(size_t)gw * 64 + lane] = r;
}

// ---------------- fused dual MFMA GEMM: out = relu?(h@Ws + nb@Wn + b) ----------

__global__ __launch_bounds__(256) void gemm128(const unsigned short* __restrict__ h,
                                               const unsigned short* __restrict__ nb,
                                               const unsigned short* __restrict__ wl,
                                               const float* __restrict__ bias,
                                               unsigned short* __restrict__ out,
                                               int M, int relu) {
    __shared__ s16x8 afr[4096];  // [ks(8)][mf(8)][lane(64)] : 64 KB
    const int tid = threadIdx.x;
    const int l = tid & 63, w = tid >> 6;
    const int r0 = blockIdx.x * 128;
    const int cg = (w * 4 + (l >> 4)) * 8;

    s16x8 th[8], tn[8];
#pragma unroll
    for (int i = 0; i < 8; ++i) {
        int r = r0 + i * 16 + (l & 15);
        if (r >= M) r = M - 1;
        th[i] = *(const s16x8*)(h + (size_t)r * 128 + cg);
        tn[i] = *(const s16x8*)(nb + (size_t)r * 128 + cg);
    }
#pragma unroll
    for (int i = 0; i < 8; ++i) {
        afr[(w * 8 + i) * 64 + l] = th[i];
        afr[((w + 4) * 8 + i) * 64 + l] = tn[i];
    }
    __syncthreads();

    const int mh = w >> 1, nh = w & 1;
    const s16x8* wf = (const s16x8*)wl;

    f32x4 acc[4][4];
#pragma unroll
    for (int i = 0; i < 4; ++i)
#pragma unroll
        for (int j = 0; j < 4; ++j) acc[i][j] = (f32x4)0.f;

#pragma unroll
    for (int ks = 0; ks < 8; ++ks) {
        s16x8 bw[4], ha[4];
#pragma unroll
        for (int nf = 0; nf < 4; ++nf) bw[nf] = wf[(ks * 8 + nh * 4 + nf) * 64 + l];
#pragma unroll
        for (int mf = 0; mf < 4; ++mf) ha[mf] = afr[(ks * 8 + mh * 4 + mf) * 64 + l];
#pragma unroll
        for (int mf = 0; mf < 4; ++mf)
#pragma unroll
            for (int nf = 0; nf < 4; ++nf)
                acc[mf][nf] = __builtin_amdgcn_mfma_f32_16x16x32_bf16(bw[nf], ha[mf],
                                                                      acc[mf][nf], 0, 0, 0);
    }

    f4 bv[4];
#pragma unroll
    for (int nf = 0; nf < 4; ++nf)
        bv[nf] = *(const f4*)&bias[nh * 64 + nf * 16 + ((l >> 4) << 2)];

#pragma unroll
    for (int mf = 0; mf < 4; ++mf) {
        int row = r0 + mh * 64 + mf * 16 + (l & 15);
        if (row >= M) continue;
#pragma unroll
        for (int nf = 0; nf < 4; ++nf) {
            int ncol = nh * 64 + nf * 16 + ((l >> 4) << 2);
            f32x4 a = acc[mf][nf];
            float v0 = a[0] + bv[nf][0], v1 = a[1] + bv[nf][1];
            float v2 = a[2] + bv[nf][2], v3 = a[3] + bv[nf][3];
            if (relu) {
                v0 = fmaxf(v0, 0.f); v1 = fmaxf(v1, 0.f);
                v2 = fmaxf(v2, 0.f); v3 = fmaxf(v3, 0.f);
            }
            uint2 p;
            p.x = (unsigned int)f2bf(v0) | ((unsigned int)f2bf(v1) << 16);
            p.y = (unsigned int)f2bf(v2) | ((unsigned int)f2bf(v3) << 16);
            *(uint2*)(out + (size_t)row * 128 + ncol) = p;
        }
    }
}

// ---------------- final MFMA GEMM 256 -> 47 (f32 out) ----------------

__global__ __launch_bounds__(256) void gemm_out47(const unsigned short* __restrict__ h,
                                                  const unsigned short* __restrict__ nb,
                                                  const unsigned short* __restrict__ wpo,
                                                  const float* __restrict__ bo,
                                                  float* __restrict__ out, int M) {
    __shared__ s16x8 afr[4096];
    const int tid = threadIdx.x;
    const int l = tid & 63, w = tid >> 6;
    const int r0 = blockIdx.x * 128;
    const int cg = (w * 4 + (l >> 4)) * 8;

    s16x8 th[8], tn[8];
#pragma unroll
    for (int i = 0; i < 8; ++i) {
        int r = r0 + i * 16 + (l & 15);
        if (r >= M) r = M - 1;
        th[i] = *(const s16x8*)(h + (size_t)r * 128 + cg);
        tn[i] = *(const s16x8*)(nb + (size_t)r * 128 + cg);
    }
#pragma unroll
    for (int i = 0; i < 8; ++i) {
        afr[(w * 8 + i) * 64 + l] = th[i];
        afr[((w + 4) * 8 + i) * 64 + l] = tn[i];
    }
    __syncthreads();

    const s16x8* wf = (const s16x8*)wpo;
    f32x4 acc[2][3];
#pragma unroll
    for (int i = 0; i < 2; ++i)
#pragma unroll
        for (int j = 0; j < 3; ++j) acc[i][j] = (f32x4)0.f;

#pragma unroll
    for (int ks = 0; ks < 8; ++ks) {
        s16x8 bw[3], ha[2];
#pragma unroll
        for (int nf = 0; nf < 3; ++nf) bw[nf] = wf[(ks * 3 + nf) * 64 + l];
#pragma unroll
        for (int mf = 0; mf < 2; ++mf) ha[mf] = afr[(ks * 8 + w * 2 + mf) * 64 + l];
#pragma unroll
        for (int mf = 0; mf < 2; ++mf)
#pragma unroll
            for (int nf = 0; nf < 3; ++nf)
                acc[mf][nf] = __builtin_amdgcn_mfma_f32_16x16x32_bf16(bw[nf], ha[mf],
                                                                      acc[mf][nf], 0, 0, 0);
    }

#pragma unroll
    for (int mf = 0; mf < 2; ++mf) {
        int row = r0 + w * 32 + mf * 16 + (l & 15);
        if (row >= M) continue;
#pragma unroll
        for (int nf = 0; nf < 3; ++nf) {
            int ncol = nf * 16 + ((l >> 4) << 2);
            f32x4 a = acc[mf][nf];
#pragma unroll
            for (int jj = 0; jj < 4; ++jj) {
                int n = ncol + jj;
                if (n < 47) out[(size_t)row * 47 + n] = a[jj] + bo[n];
            }
        }
    }
}

// ---------------- launch ----------------

static inline char* alignp(char* p) {
    return (char*)(((size_t)p + 255) & ~(size_t)255);
}

extern "C" void kernel_launch(void* const* d_in, const int* in_sizes, int n_in,
                              void* d_out, int out_size, void* d_ws, size_t ws_size,
                              hipStream_t stream) {
    const float* x = (const float*)d_in[0];
    const int* src = (const int*)d_in[1];
    const int* dst = (const int*)d_in[2];
    const float* w_self = (const float*)d_in[3];
    const float* w_neigh = (const float*)d_in[4];
    const float* b = (const float*)d_in[5];
    const float* wso = (const float*)d_in[6];
    const float* wno = (const float*)d_in[7];
    const float* bo = (const float*)d_in[8];
    float* out = (float*)d_out;

    const int N = N_NODES;
    const int E = in_sizes[1];

    char* w = (char*)d_ws;
    unsigned short* xb = (unsigned short*)w;  w = alignp(w + (size_t)N * 128 * 2);
    unsigned short* hA = (unsigned short*)w;  w = alignp(w + (size_t)N * 128 * 2);
    unsigned short* hB = (unsigned short*)w;  w = alignp(w + (size_t)N * 128 * 2);
    unsigned short* wp = (unsigned short*)w;  w = alignp(w + (size_t)5 * 32768 * 2);
    unsigned short* wpo = (unsigned short*)w; w = alignp(w + (size_t)1536 * 8 * 2);
    int* rp = (int*)w;       w = alignp(w + (size_t)(N + 4) * 4);
    int* col = (int*)w;      w = alignp(w + (size_t)E * 4);
    int* histG = (int*)w;    w = alignp(w + (size_t)NBUCK * NB1 * 4);
    float* invd = (float*)w; w = alignp(w + (size_t)N * 4);

    // ebuf (packed edges, E*4 bytes) aliases hB: hB is first touched at layer-1
    // aggregation, long after k_csr has consumed ebuf.
    unsigned int* ebuf = (unsigned int*)hB;

    // CSR build (bucketed, L2-local scatters)
    k_hist<<<NB1, 256, 0, stream>>>(dst, histG, E);
    k_scanB<<<1, 1024, 0, stream>>>(histG);
    k_place<<<NB1, 256, 0, stream>>>(src, dst, histG, ebuf, E);
    k_csr<<<NBUCK, 256, 0, stream>>>(ebuf, histG, rp, col, invd, N, E);

    // dtype prep
    k_cvt<<<(N * 128 / 8 + 255) / 256, 256, 0, stream>>>(x, xb, N * 128 / 8);
    k_prepw<<<(5 * 4096 + 255) / 256, 256, 0, stream>>>(w_self, w_neigh, wp);
    k_prepwo<<<6, 256, 0, stream>>>(wso, wno, wpo);

    const int aggBlocks = (N * 64 + 255) / 256;   // 25000
    const int gemmBlocks = (N + 127) / 128;       // 782

    // layer 0 (no relu): agg(xb)->hA, gemm writes in-place into hA
    k_agg<<<aggBlocks, 256, 0, stream>>>(xb, rp, col, invd, hA, N);
    gemm128<<<gemmBlocks, 256, 0, stream>>>(xb, hA, wp, b, hA, N, 0);

    unsigned short* cur = hA;
    unsigned short* oth = hB;
    for (int lyr = 1; lyr < 5; ++lyr) {
        k_agg<<<aggBlocks, 256, 0, stream>>>(cur, rp, col, invd, oth, N);
        gemm128<<<gemmBlocks, 256, 0, stream>>>(cur, oth, wp + (size_t)lyr * 32768,
                                                b + (size_t)lyr * 128, oth, N, 1);
        unsigned short* t = cur; cur = oth; oth = t;
    }

    k_agg<<<aggBlocks, 256, 0, stream>>>(cur, rp, col, invd, oth, N);
    gemm_out47<<<gemmBlocks, 256, 0, stream>>>(cur, oth, wpo, bo, out, N);
}